// Round 1
// baseline (468.340 us; speedup 1.0000x reference)
//
#include <hip/hip_runtime.h>
#include <stdint.h>

#define IN_F 2048
#define OUT_F 2048
#define MTOK 16384   // 4 * 4096 tokens

typedef __attribute__((ext_vector_type(8))) __bf16 bf16x8;
typedef __attribute__((ext_vector_type(4))) float f32x4;
typedef __attribute__((ext_vector_type(4))) unsigned short us4;

typedef const __attribute__((address_space(1))) void g_void;
typedef __attribute__((address_space(3))) void l_void;

// 16B async global->LDS (wave-uniform LDS base + lane*16; swizzle on global src)
__device__ __forceinline__ void async16(void* lds, const void* g) {
    __builtin_amdgcn_global_load_lds((g_void*)(uintptr_t)g, (l_void*)(uintptr_t)lds, 16, 0, 0);
}

// fp32 -> bf16 round-to-nearest-even
__device__ __forceinline__ unsigned short f2bf(float x) {
    union { float f; uint32_t u; } v; v.f = x;
    uint32_t r = v.u + 0x7fffu + ((v.u >> 16) & 1u);
    return (unsigned short)(r >> 16);
}

// ---------------------------------------------------------------------------
// K0: k_fold_conv.
// Blocks [0,1024): exact fp32 weight fold. The entire butterfly
// (stage1 -> shuffle -> mix -> stage2) is one linear map; fold it into
// B2[o2][i] so the main op becomes a single GEMM out = x @ B2^T.
//   M1[o][g*64+c]     = sum_d W1[g][c][d] * Bp[o][g*64+d]
//   B2[g2*64+d2][i]   = sum_c2 W2[g2][c2][d2] * M1[g2*64+c2][i]
// with Bp[o][i] = mix_w[o][((i&31)<<6)|(i>>5)] (shuffle folded; for
// i=g*64+d: column = ((d&31)<<6) | (g<<1) | (d>>5)).
// Block (g = bx&31, rt = bx>>5) computes B2[rt*64..+64][g*64..+64]; the
// M1 tile it needs is exactly rows rt*64..+64 x cols g*64..+64 -> kept in
// LDS, never materialized in HBM (ws stays at 72 MB).
// Blocks [1024,3072): X fp32 -> bf16 convert (memory-bound stream).
// ---------------------------------------------------------------------------
#define FP 68   // padded fp32 row length: 272B rows, 16B-aligned, spreads banks

__global__ __launch_bounds__(256) void k_fold_conv(
    const float* __restrict__ X, const float* __restrict__ s1,
    const float* __restrict__ s2, const float* __restrict__ MW,
    unsigned short* __restrict__ Xb, unsigned short* __restrict__ Bb) {
    __shared__ float lds[3 * 64 * FP];   // 52.2 KB
    const int t = threadIdx.x;
    const int bx = blockIdx.x;

    if (bx >= 1024) {
        // ---- X convert: 2048 blocks * 256 thr * 16 float4 = 8.39M float4 ----
        const int gid = (bx - 1024) * 256 + t;
        const float4* src = (const float4*)X;
        us4* dst = (us4*)Xb;
#pragma unroll
        for (int k = 0; k < 16; ++k) {
            int idx = k * (2048 * 256) + gid;
            float4 v = src[idx];
            us4 o;
            o[0] = f2bf(v.x); o[1] = f2bf(v.y); o[2] = f2bf(v.z); o[3] = f2bf(v.w);
            dst[idx] = o;
        }
        return;
    }

    float* Wl  = lds;             // [64][FP]: W1 rows, later reused for W2^T
    float* Bpl = lds + 64 * FP;   // [64][FP]: permuted-mix tile Bp[o'][d]
    float* M1t = lds + 128 * FP;  // [64][FP]: M1 transposed [c][o']
    const int g  = bx & 31;       // column block: i = g*64+c
    const int rt = bx >> 5;       // row tile: rows rt*64..+64 (g2 == rt)

    // step 1: Wl[c][d] = stage1[g*64+c][d]   (coalesced float4)
#pragma unroll
    for (int q = 0; q < 4; ++q) {
        int id = q * 256 + t;               // [0,1024)
        int c = id >> 4, d4 = id & 15;
        float4 v = *(const float4*)(s1 + (size_t)(g * 64 + c) * 64 + d4 * 4);
        *(float4*)&Wl[c * FP + d4 * 4] = v;
    }
    // step 2: Bpl[o'][d] = MW[rt*64+o'][((d&31)<<6)|(g<<1)|(d>>5)]
    // pairs (d, d+32) are adjacent floats in MW -> float2 loads
#pragma unroll
    for (int q = 0; q < 8; ++q) {
        int id = q * 256 + t;               // [0,2048)
        int o = id >> 5, b = id & 31;
        float2 v = *(const float2*)(MW + (size_t)(rt * 64 + o) * 2048 + b * 64 + g * 2);
        Bpl[o * FP + b]      = v.x;
        Bpl[o * FP + b + 32] = v.y;
    }
    __syncthreads();

    // step 3: M1t[c][o'] = sum_d Bpl[o'][d] * Wl[c][d]   (fp32, exact)
    {
        const int co = (t & 15) * 4, oo = (t >> 4) * 4;
        float acc[4][4] = {};
#pragma unroll
        for (int dc = 0; dc < 16; ++dc) {
            float4 bv[4], wv[4];
#pragma unroll
            for (int i = 0; i < 4; ++i) bv[i] = *(const float4*)&Bpl[(oo + i) * FP + dc * 4];
#pragma unroll
            for (int j = 0; j < 4; ++j) wv[j] = *(const float4*)&Wl[(co + j) * FP + dc * 4];
#pragma unroll
            for (int i = 0; i < 4; ++i)
#pragma unroll
                for (int j = 0; j < 4; ++j)
                    acc[i][j] += bv[i].x * wv[j].x + bv[i].y * wv[j].y
                               + bv[i].z * wv[j].z + bv[i].w * wv[j].w;
        }
#pragma unroll
        for (int i = 0; i < 4; ++i)
#pragma unroll
            for (int j = 0; j < 4; ++j)
                M1t[(co + j) * FP + oo + i] = acc[i][j];
    }
    __syncthreads();   // Wl reads done before overwrite

    // step 4: Wl <- W2t[d2][c2] = stage2[rt*64+c2][d2]  (coalesced 4B reads)
#pragma unroll
    for (int q = 0; q < 16; ++q) {
        int id = q * 256 + t;               // [0,4096)
        int d2 = id & 63, c2 = id >> 6;
        Wl[d2 * FP + c2] = s2[(size_t)(rt * 64 + c2) * 64 + d2];
    }
    __syncthreads();

    // step 5: B2[rt*64+d2][g*64+c] = sum_c2 Wl[d2][c2] * M1t[c][c2] -> bf16
    {
        const int cco = (t & 15) * 4, d2o = (t >> 4) * 4;
        float acc[4][4] = {};
#pragma unroll
        for (int kc = 0; kc < 16; ++kc) {
            float4 wv[4], mv[4];
#pragma unroll
            for (int i = 0; i < 4; ++i) wv[i] = *(const float4*)&Wl[(d2o + i) * FP + kc * 4];
#pragma unroll
            for (int j = 0; j < 4; ++j) mv[j] = *(const float4*)&M1t[(cco + j) * FP + kc * 4];
#pragma unroll
            for (int i = 0; i < 4; ++i)
#pragma unroll
                for (int j = 0; j < 4; ++j)
                    acc[i][j] += wv[i].x * mv[j].x + wv[i].y * mv[j].y
                               + wv[i].z * mv[j].z + wv[i].w * mv[j].w;
        }
#pragma unroll
        for (int i = 0; i < 4; ++i) {
            us4 o;
            o[0] = f2bf(acc[i][0]); o[1] = f2bf(acc[i][1]);
            o[2] = f2bf(acc[i][2]); o[3] = f2bf(acc[i][3]);
            *(us4*)(Bb + (size_t)(rt * 64 + d2o + i) * 2048 + g * 64 + cco) = o;
        }
    }
}

// ---------------------------------------------------------------------------
// K1: the single GEMM. C[m][o2] = sum_i Xb[m][i] * Bb[o2][i], fp32 out.
// Identical to the proven k_mix_gemm (XOR-swizzled LDS, 0 bank conflicts;
// temporal block remap for A-strip L2 reuse) with the stage2 epilogue
// deleted — acc writes C directly.
// ---------------------------------------------------------------------------
__global__ __launch_bounds__(256, 2) void k_gemm(
    const unsigned short* __restrict__ A, const unsigned short* __restrict__ B,
    float* __restrict__ C) {
    __shared__ unsigned short smem[16384];   // As 16KB | Bs 16KB
    unsigned short* As = smem;
    unsigned short* Bs = smem + 8192;
    const int t = threadIdx.x;
    const int lane = t & 63, wave = t >> 6;
    const int quad = lane >> 4, l16 = lane & 15;
    const int mw = wave & 1, nw = wave >> 1;
    // temporal remap: dispatch is x-fastest; lin..lin+15 = one m-strip x all n
    const int lin = blockIdx.y * 128 + blockIdx.x;
    const int m0 = (lin >> 4) * 128;
    const int n0 = (lin & 15) * 128;
    const int rr = t >> 3, chunk = t & 7;      // 32 rows x 8 16B-chunks per issue
    const int gsw = (chunk ^ (rr & 7)) * 8;    // swizzled source chunk (shorts)
    const int lsw = l16 & 7;                   // read-side swizzle key

    f32x4 acc[4][4];
#pragma unroll
    for (int i = 0; i < 4; ++i)
#pragma unroll
        for (int j = 0; j < 4; ++j) acc[i][j] = (f32x4)0.f;

    for (int kb = 0; kb < IN_F; kb += 64) {
#pragma unroll
        for (int q = 0; q < 4; ++q) {
            int r = q * 32 + rr;
            async16((char*)As + (size_t)(q * 4096 + t * 16),
                    A + (size_t)(m0 + r) * IN_F + kb + gsw);
            async16((char*)Bs + (size_t)(q * 4096 + t * 16),
                    B + (size_t)(n0 + r) * IN_F + kb + gsw);
        }
        __syncthreads();
#pragma unroll
        for (int ks = 0; ks < 2; ++ks) {
            bf16x8 af[4], bfr[4];
#pragma unroll
            for (int i = 0; i < 4; ++i)
                af[i] = *(const bf16x8*)(As + (mw * 64 + i * 16 + l16) * 64
                                            + (((ks * 4 + quad) ^ lsw) * 8));
#pragma unroll
            for (int j = 0; j < 4; ++j)
                bfr[j] = *(const bf16x8*)(Bs + (nw * 64 + j * 16 + l16) * 64
                                             + (((ks * 4 + quad) ^ lsw) * 8));
#pragma unroll
            for (int i = 0; i < 4; ++i)
#pragma unroll
                for (int j = 0; j < 4; ++j)
                    acc[i][j] = __builtin_amdgcn_mfma_f32_16x16x32_bf16(af[i], bfr[j], acc[i][j], 0, 0, 0);
        }
        __syncthreads();
    }

    // direct C write (C/D layout: row = quad*4+r, col = l16)
#pragma unroll
    for (int i = 0; i < 4; ++i)
#pragma unroll
        for (int j = 0; j < 4; ++j) {
            float* Cp = C + (size_t)(m0 + mw * 64 + i * 16 + quad * 4) * OUT_F
                          + (n0 + nw * 64 + j * 16 + l16);
#pragma unroll
            for (int r = 0; r < 4; ++r) Cp[(size_t)r * OUT_F] = acc[i][j][r];
        }
}

// ---------------------------------------------------------------------------
extern "C" void kernel_launch(void* const* d_in, const int* in_sizes, int n_in,
                              void* d_out, int out_size, void* d_ws, size_t ws_size,
                              hipStream_t stream) {
    const float* x  = (const float*)d_in[0];
    const float* s1 = (const float*)d_in[1];
    const float* s2 = (const float*)d_in[2];
    const float* mw = (const float*)d_in[3];
    float* out = (float*)d_out;

    char* ws = (char*)d_ws;
    unsigned short* Xb = (unsigned short*)ws;                              // 64 MB
    unsigned short* Bb = (unsigned short*)(ws + (size_t)MTOK * IN_F * 2);  // 8 MB

    k_fold_conv<<<3072, 256, 0, stream>>>(x, s1, s2, mw, Xb, Bb);
    k_gemm<<<dim3(128, 16), 256, 0, stream>>>(Xb, Bb, out);
}

// Round 3
// 419.036 us; speedup vs baseline: 1.1177x; 1.1177x over previous
//
#include <hip/hip_runtime.h>
#include <stdint.h>

#define IN_F 2048
#define OUT_F 2048
#define MTOK 16384   // 4 * 4096 tokens

typedef __attribute__((ext_vector_type(8))) __bf16 bf16x8;
typedef __attribute__((ext_vector_type(4))) float f32x4;
typedef __attribute__((ext_vector_type(4))) unsigned short us4;

typedef const __attribute__((address_space(1))) void g_void;
typedef __attribute__((address_space(3))) void l_void;

// 16B async global->LDS (wave-uniform LDS base + lane*16; swizzle on global src)
__device__ __forceinline__ void async16(void* lds, const void* g) {
    __builtin_amdgcn_global_load_lds((g_void*)(uintptr_t)g, (l_void*)(uintptr_t)lds, 16, 0, 0);
}

// fp32 -> bf16 round-to-nearest-even
__device__ __forceinline__ unsigned short f2bf(float x) {
    union { float f; uint32_t u; } v; v.f = x;
    uint32_t r = v.u + 0x7fffu + ((v.u >> 16) & 1u);
    return (unsigned short)(r >> 16);
}

// ---------------------------------------------------------------------------
// K_convert: X fp32 -> bf16. Pure stream, NO LDS (full occupancy).
// 2048 blocks * 256 thr * 16 float4 = 8.39M float4 = 16384*2048 floats.
// ---------------------------------------------------------------------------
__global__ __launch_bounds__(256) void k_convert(
    const float* __restrict__ X, unsigned short* __restrict__ Xb) {
    const int gid = blockIdx.x * 256 + threadIdx.x;
    const float4* src = (const float4*)X;
    us4* dst = (us4*)Xb;
#pragma unroll
    for (int k = 0; k < 16; ++k) {
        int idx = k * (2048 * 256) + gid;
        float4 v = src[idx];
        us4 o;
        o[0] = f2bf(v.x); o[1] = f2bf(v.y); o[2] = f2bf(v.z); o[3] = f2bf(v.w);
        dst[idx] = o;
    }
}

// ---------------------------------------------------------------------------
// K_fold: exact fp32 weight fold (butterfly = one linear map):
//   M1[o][g*64+c]   = sum_d W1[g][c][d] * Bp[o][g*64+d]
//   B2[g2*64+d2][i] = sum_c2 W2[g2][c2][d2] * M1[g2*64+c2][i]
// Bp[o][g*64+d] = mix_w[o][((d&31)<<6)|(g<<1)|(d>>5)] (shuffle folded).
// Block (g = bx&31, rt = bx>>5) computes B2[rt*64..+64][g*64..+64]; M1 tile
// lives only in LDS. 2 buffers (34.8KB -> 4 blocks/CU).
// Bank-conflict fixes vs R1: per-lane k-stagger dce=(dc+l)&15 on both inner
// loops (lane-row operand -> h-broadcast, other -> <=4-way); W2 kept
// untransposed and read row-per-s (aligned b128, 2-way free).
// ---------------------------------------------------------------------------
#define FP 68   // padded fp32 row: 272B, 16B-aligned

__global__ __launch_bounds__(256) void k_fold(
    const float* __restrict__ s1, const float* __restrict__ s2,
    const float* __restrict__ MW, unsigned short* __restrict__ Bb) {
    __shared__ float B0[64 * FP];   // W1[c][d]  -> later M1t[c][o]
    __shared__ float B1[64 * FP];   // Bp[o][d]  -> later W2[c2][d2] (as loaded)
    const int t = threadIdx.x;
    const int g  = blockIdx.x & 31;
    const int rt = blockIdx.x >> 5;
    const int l = t & 15, h = t >> 4;    // h in [0,16)

    // B0[c][d] = stage1[g*64+c][d]  (coalesced float4)
#pragma unroll
    for (int q = 0; q < 4; ++q) {
        int id = q * 256 + t;            // [0,1024)
        int c = id >> 4, d4 = id & 15;
        *(float4*)&B0[c * FP + d4 * 4] =
            *(const float4*)(s1 + (size_t)(g * 64 + c) * 64 + d4 * 4);
    }
    // B1[o][d] = Bp tile; (d, d+32) are adjacent floats in MW -> float2
#pragma unroll
    for (int q = 0; q < 8; ++q) {
        int id = q * 256 + t;            // [0,2048)
        int o = id >> 5, b = id & 31;
        float2 v = *(const float2*)(MW + (size_t)(rt * 64 + o) * 2048 + b * 64 + g * 2);
        B1[o * FP + b]      = v.x;
        B1[o * FP + b + 32] = v.y;
    }
    __syncthreads();

    // step 3: M1t[c][o] = sum_d Bp[o][d] * W1[c][d]; thread owns c=4l..+3, o=4h..+3
    float acc[4][4];
#pragma unroll
    for (int i = 0; i < 4; ++i)
#pragma unroll
        for (int j = 0; j < 4; ++j) acc[i][j] = 0.f;
    {
        const int co = l * 4, oo = h * 4;
#pragma unroll
        for (int dc = 0; dc < 16; ++dc) {
            const int dce = (dc + l) & 15;           // lane k-stagger
            float4 bv[4], wv[4];
#pragma unroll
            for (int i = 0; i < 4; ++i) bv[i] = *(const float4*)&B1[(oo + i) * FP + dce * 4];
#pragma unroll
            for (int j = 0; j < 4; ++j) wv[j] = *(const float4*)&B0[(co + j) * FP + dce * 4];
#pragma unroll
            for (int i = 0; i < 4; ++i)
#pragma unroll
                for (int j = 0; j < 4; ++j)
                    acc[i][j] += bv[i].x * wv[j].x + bv[i].y * wv[j].y
                               + bv[i].z * wv[j].z + bv[i].w * wv[j].w;
        }
    }
    __syncthreads();   // all reads of B0(W1)/B1(Bp) done

    // write M1t[c][o] into B0 (float4 along o); load W2 into B1 as-is
    {
        const int co = l * 4, oo = h * 4;
#pragma unroll
        for (int j = 0; j < 4; ++j) {
            float4 v; v.x = acc[0][j]; v.y = acc[1][j]; v.z = acc[2][j]; v.w = acc[3][j];
            *(float4*)&B0[(co + j) * FP + oo] = v;
        }
    }
#pragma unroll
    for (int q = 0; q < 4; ++q) {
        int id = q * 256 + t;            // [0,1024)
        int c2 = id >> 4, d4 = id & 15;
        *(float4*)&B1[c2 * FP + d4 * 4] =
            *(const float4*)(s2 + (size_t)(rt * 64 + c2) * 64 + d4 * 4);
    }
    __syncthreads();

    // step 5: B2[d2][c] = sum_o W2[o][d2] * M1t[c][o]; thread owns d2=4l..+3, c=4h..+3
    {
        const int d2o = l * 4, cco = h * 4;
#pragma unroll
        for (int i = 0; i < 4; ++i)
#pragma unroll
            for (int j = 0; j < 4; ++j) acc[i][j] = 0.f;
#pragma unroll
        for (int kc = 0; kc < 16; ++kc) {
            const int kce = (kc + l) & 15;           // lane k-stagger
            float4 wv4[4], mv[4];
#pragma unroll
            for (int s = 0; s < 4; ++s) wv4[s] = *(const float4*)&B1[(kce * 4 + s) * FP + d2o];
#pragma unroll
            for (int j = 0; j < 4; ++j) mv[j] = *(const float4*)&B0[(cco + j) * FP + kce * 4];
#pragma unroll
            for (int i = 0; i < 4; ++i)
#pragma unroll
                for (int j = 0; j < 4; ++j)
                    acc[i][j] += wv4[0][i] * mv[j].x + wv4[1][i] * mv[j].y
                               + wv4[2][i] * mv[j].z + wv4[3][i] * mv[j].w;
        }
#pragma unroll
        for (int i = 0; i < 4; ++i) {
            us4 o;
            o[0] = f2bf(acc[i][0]); o[1] = f2bf(acc[i][1]);
            o[2] = f2bf(acc[i][2]); o[3] = f2bf(acc[i][3]);
            *(us4*)(Bb + (size_t)(rt * 64 + d2o + i) * 2048 + g * 64 + cco) = o;
        }
    }
}

// ---------------------------------------------------------------------------
// K1: the single GEMM. C[m][o2] = sum_i Xb[m][i] * Bb[o2][i], fp32 out.
// Proven structure (XOR-swizzled LDS, 0 bank conflicts). Block mapping:
// bijective chunked XCD remap (2048%8==0) so the 16 blocks sharing an A
// m-strip land on ONE XCD's L2, then temporal remap within.
// ---------------------------------------------------------------------------
__global__ __launch_bounds__(256, 2) void k_gemm(
    const unsigned short* __restrict__ A, const unsigned short* __restrict__ B,
    float* __restrict__ C) {
    __shared__ unsigned short smem[16384];   // As 16KB | Bs 16KB
    unsigned short* As = smem;
    unsigned short* Bs = smem + 8192;
    const int t = threadIdx.x;
    const int lane = t & 63, wave = t >> 6;
    const int quad = lane >> 4, l16 = lane & 15;
    const int mw = wave & 1, nw = wave >> 1;
    const int orig = blockIdx.y * 128 + blockIdx.x;
    const int lin = (orig & 7) * 256 + (orig >> 3);   // chunked XCD swizzle
    const int m0 = (lin >> 4) * 128;
    const int n0 = (lin & 15) * 128;
    const int rr = t >> 3, chunk = t & 7;      // 32 rows x 8 16B-chunks per issue
    const int gsw = (chunk ^ (rr & 7)) * 8;    // swizzled source chunk (shorts)
    const int lsw = l16 & 7;                   // read-side swizzle key

    f32x4 acc[4][4];
#pragma unroll
    for (int i = 0; i < 4; ++i)
#pragma unroll
        for (int j = 0; j < 4; ++j) acc[i][j] = (f32x4)0.f;

    for (int kb = 0; kb < IN_F; kb += 64) {
#pragma unroll
        for (int q = 0; q < 4; ++q) {
            int r = q * 32 + rr;
            async16((char*)As + (size_t)(q * 4096 + t * 16),
                    A + (size_t)(m0 + r) * IN_F + kb + gsw);
            async16((char*)Bs + (size_t)(q * 4096 + t * 16),
                    B + (size_t)(n0 + r) * IN_F + kb + gsw);
        }
        __syncthreads();
#pragma unroll
        for (int ks = 0; ks < 2; ++ks) {
            bf16x8 af[4], bfr[4];
#pragma unroll
            for (int i = 0; i < 4; ++i)
                af[i] = *(const bf16x8*)(As + (mw * 64 + i * 16 + l16) * 64
                                            + (((ks * 4 + quad) ^ lsw) * 8));
#pragma unroll
            for (int j = 0; j < 4; ++j)
                bfr[j] = *(const bf16x8*)(Bs + (nw * 64 + j * 16 + l16) * 64
                                             + (((ks * 4 + quad) ^ lsw) * 8));
#pragma unroll
            for (int i = 0; i < 4; ++i)
#pragma unroll
                for (int j = 0; j < 4; ++j)
                    acc[i][j] = __builtin_amdgcn_mfma_f32_16x16x32_bf16(af[i], bfr[j], acc[i][j], 0, 0, 0);
        }
        __syncthreads();
    }

    // direct C write (C/D layout: row = quad*4+r, col = l16)
#pragma unroll
    for (int i = 0; i < 4; ++i)
#pragma unroll
        for (int j = 0; j < 4; ++j) {
            float* Cp = C + (size_t)(m0 + mw * 64 + i * 16 + quad * 4) * OUT_F
                          + (n0 + nw * 64 + j * 16 + l16);
#pragma unroll
            for (int r = 0; r < 4; ++r) Cp[(size_t)r * OUT_F] = acc[i][j][r];
        }
}

// ---------------------------------------------------------------------------
extern "C" void kernel_launch(void* const* d_in, const int* in_sizes, int n_in,
                              void* d_out, int out_size, void* d_ws, size_t ws_size,
                              hipStream_t stream) {
    const float* x  = (const float*)d_in[0];
    const float* s1 = (const float*)d_in[1];
    const float* s2 = (const float*)d_in[2];
    const float* mw = (const float*)d_in[3];
    float* out = (float*)d_out;

    char* ws = (char*)d_ws;
    unsigned short* Xb = (unsigned short*)ws;                              // 64 MB
    unsigned short* Bb = (unsigned short*)(ws + (size_t)MTOK * IN_F * 2);  // 8 MB

    k_fold<<<1024, 256, 0, stream>>>(s1, s2, mw, Bb);
    k_convert<<<2048, 256, 0, stream>>>(x, Xb);
    k_gemm<<<dim3(128, 16), 256, 0, stream>>>(Xb, Bb, out);
}